// Round 1
// baseline (16.536 us; speedup 1.0000x reference)
//
#include <hip/hip_runtime.h>

#define BATCH 2048
#define UNITS 512
#define DIM   64
#define TB    64   // batch tile
#define TU    64   // unit tile

// word index within a [64][64] f32 tile, row k, col c, 16B-granule XOR swizzle
__device__ __forceinline__ int swz(int k, int c) {
  return k * 64 + ((((c >> 2) ^ (k & 15)) << 2) | (c & 3));
}

extern "C" __global__ void __launch_bounds__(256)
sausage_fused(const float* __restrict__ x, const float* __restrict__ q1,
              const float* __restrict__ q2, const float* __restrict__ r,
              float* __restrict__ out)
{
  __shared__ float sxT[64 * 64];   // x^T  [k][b], swizzled
  __shared__ float s12[64 * 64];   // q12^T [k][u], swizzled
  __shared__ float sq2[64 * 64];   // q2^T  [k][u], swizzled
  __shared__ float  su_w[64], su_nq2[64], su_q2n[64], su_invd[64];
  __shared__ double sd_t[64], sd_q12n[64];
  __shared__ float  sb_xn[64];

  const int tid = threadIdx.x;
  const int b0 = blockIdx.x * TB;
  const int u0 = blockIdx.y * TU;

  // ---------------- staging: global (row-major) -> LDS (k-major, swizzled) ----
  {
    const int k  = tid & 63;           // column (k) this thread loads
    const int rg = (tid >> 6) << 2;    // row-group base within a 16-row pass
    #pragma unroll
    for (int p = 0; p < 4; ++p) {
      const int row = p * 16 + rg;                   // multiple of 4
      const int g   = (((row >> 2) ^ (k & 15)) << 2);
      // x tile: rows b0+row..+3, column k  (coalesced 256B per wave per load)
      float xv0 = x[(b0 + row + 0) * DIM + k];
      float xv1 = x[(b0 + row + 1) * DIM + k];
      float xv2 = x[(b0 + row + 2) * DIM + k];
      float xv3 = x[(b0 + row + 3) * DIM + k];
      *reinterpret_cast<float4*>(&sxT[k * 64 + g]) = make_float4(xv0, xv1, xv2, xv3);
      // q tiles: rows u0+row..+3, column k
      float a0 = q1[(u0 + row + 0) * DIM + k], c0 = q2[(u0 + row + 0) * DIM + k];
      float a1 = q1[(u0 + row + 1) * DIM + k], c1 = q2[(u0 + row + 1) * DIM + k];
      float a2 = q1[(u0 + row + 2) * DIM + k], c2 = q2[(u0 + row + 2) * DIM + k];
      float a3 = q1[(u0 + row + 3) * DIM + k], c3 = q2[(u0 + row + 3) * DIM + k];
      *reinterpret_cast<float4*>(&s12[k * 64 + g]) =
          make_float4(c0 - a0, c1 - a1, c2 - a2, c3 - a3);
      *reinterpret_cast<float4*>(&sq2[k * 64 + g]) = make_float4(c0, c1, c2, c3);
    }
  }
  __syncthreads();

  // ---------------- per-u / per-b scalars (waves 0 and 1) --------------------
  if (tid < 64) {
    const int u = tid;
    double w = 0.0, nq2 = 0.0;
    float q2n = 0.0f;
    #pragma unroll 8
    for (int k = 0; k < 64; ++k) {
      const float a = s12[swz(k, u)];
      const float c = sq2[swz(k, u)];
      w   += (double)c * (double)a;
      nq2 += (double)a * (double)a;
      q2n += c * c;
    }
    sd_t[u]    = w - nq2;            // t = q1.q12 = w - ||q12||^2 (fp64)
    sd_q12n[u] = sqrt(nq2);
    su_w[u]    = (float)w;
    su_nq2[u]  = (float)nq2;
    su_q2n[u]  = q2n;
    const float rv = r[u0 + u];
    su_invd[u] = 1.0f / (64.0f * rv * rv);
  } else if (tid < 128) {
    const int b = tid - 64;
    float xn = 0.0f;
    #pragma unroll 8
    for (int k = 0; k < 64; ++k) {
      const float v = sxT[swz(k, b)];
      xn += v * v;
    }
    sb_xn[b] = xn;
  }
  __syncthreads();

  // ---------------- main compute: micro-tile 4(b) x 4(u) per thread ----------
  const int txu = tid & 15;   // u granule (fast dim -> coalesced stores)
  const int tyb = tid >> 4;   // b granule
  double aa[4][4];            // a = x . q12   (fp64: feeds discontinuous branch)
  float  bb[4][4];            // b2 = x . q2
  #pragma unroll
  for (int i = 0; i < 4; ++i)
    #pragma unroll
    for (int j = 0; j < 4; ++j) { aa[i][j] = 0.0; bb[i][j] = 0.0f; }

  #pragma unroll 8
  for (int k = 0; k < 64; ++k) {
    const int sw = k & 15;
    const float4 xv = *reinterpret_cast<const float4*>(&sxT[k * 64 + ((tyb ^ sw) << 2)]);
    const float4 qv = *reinterpret_cast<const float4*>(&s12[k * 64 + ((txu ^ sw) << 2)]);
    const float4 cv = *reinterpret_cast<const float4*>(&sq2[k * 64 + ((txu ^ sw) << 2)]);
    const float xs[4] = {xv.x, xv.y, xv.z, xv.w};
    const float qs[4] = {qv.x, qv.y, qv.z, qv.w};
    const float cs[4] = {cv.x, cv.y, cv.z, cv.w};
    double xd[4], qd[4];
    #pragma unroll
    for (int i = 0; i < 4; ++i) { xd[i] = (double)xs[i]; qd[i] = (double)qs[i]; }
    #pragma unroll
    for (int i = 0; i < 4; ++i)
      #pragma unroll
      for (int j = 0; j < 4; ++j) {
        aa[i][j] += xd[i] * qd[j];
        bb[i][j] += xs[i] * cs[j];
      }
  }

  // ---------------- epilogue + coalesced float4 stores -----------------------
  #pragma unroll
  for (int i = 0; i < 4; ++i) {
    const int bl = (tyb << 2) + i;
    float o[4];
    #pragma unroll
    for (int j = 0; j < 4; ++j) {
      const int ul = (txu << 2) + j;
      const double a = aa[i][j];
      const double s = a - sd_t[ul];
      float l;
      if (s < 0.0)                l = 1.0f;
      else if (s < sd_q12n[ul])   l = (float)s;   // k_norm = |s| = s here
      else                        l = 0.0f;
      const float dsq = sb_xn[bl] - 2.0f * bb[i][j] + su_q2n[ul]
                      + 2.0f * l * ((float)a - su_w[ul]) + l * l * su_nq2[ul];
      o[j] = __expf(-dsq * su_invd[ul]);
    }
    *reinterpret_cast<float4*>(&out[(b0 + bl) * UNITS + u0 + (txu << 2)]) =
        make_float4(o[0], o[1], o[2], o[3]);
  }
}

extern "C" void kernel_launch(void* const* d_in, const int* in_sizes, int n_in,
                              void* d_out, int out_size, void* d_ws, size_t ws_size,
                              hipStream_t stream) {
  const float* x  = (const float*)d_in[0];
  const float* q1 = (const float*)d_in[1];
  const float* q2 = (const float*)d_in[2];
  const float* r  = (const float*)d_in[3];
  float* out = (float*)d_out;
  dim3 grid(BATCH / TB, UNITS / TU);   // (32, 8) = 256 blocks, 1 per CU
  sausage_fused<<<grid, 256, 0, stream>>>(x, q1, q2, r, out);
}